// Round 1
// baseline (370.809 us; speedup 1.0000x reference)
//
#include <hip/hip_runtime.h>

// Problem constants (match reference)
constexpr int H = 1024, W = 1024, C = 128, N_ITER = 8;
constexpr int TPB = 256;          // threads per block
constexpr int PPT = 4;            // pixels (columns) per thread; TPB*PPT == W

// One block per image row. Each thread owns 4 columns spaced by 256 (coalesced
// heatmap loads). Clusters cached in LDS as float2. Per-cluster dx^2 is
// row-constant -> computed once per cluster and reused across the 4 pixels.
// argmin key = max(1, d2): monotone-equivalent to max(1, sqrt(d2)); strict '<'
// keeps first index on ties (jnp.argmin semantics). One sqrt per pixel at the
// end. Scatter-add: LDS accumulators then one global atomic per slot per block.
__global__ __launch_bounds__(TPB) void kmeans_step(
    const float* __restrict__ cur,      // [C,2] current cluster coords
    const float* __restrict__ heatmap,  // [H,W]
    float* __restrict__ next)           // [C,2] output accumulators (pre-zeroed)
{
    __shared__ float2 cls[C];
    __shared__ float  acc[2 * C];       // 2*C == 256 == TPB

    const int tid = threadIdx.x;
    if (tid < C) {
        const float2* cur2 = (const float2*)cur;
        cls[tid] = cur2[tid];
    }
    acc[tid] = 0.0f;
    __syncthreads();

    const int row = blockIdx.x;
    const float fr = (float)row;
    const float* hrow = heatmap + (size_t)row * W;

    float colf[PPT], hval[PPT], best[PPT];
    int   bi[PPT];
#pragma unroll
    for (int p = 0; p < PPT; ++p) {
        const int c = tid + p * TPB;
        colf[p] = (float)c;
        hval[p] = hrow[c];
        best[p] = 3.402823466e38f;
        bi[p]   = 0;
    }

#pragma unroll 8
    for (int ci = 0; ci < C; ++ci) {
        const float2 cl = cls[ci];
        const float dx  = fr - cl.x;
        const float dx2 = dx * dx;
#pragma unroll
        for (int p = 0; p < PPT; ++p) {
            const float dy  = colf[p] - cl.y;
            const float d2  = fmaf(dy, dy, dx2);
            const float key = fmaxf(d2, 1.0f);     // clamp before compare
            const bool  lt  = key < best[p];       // strict <: first-index ties
            bi[p]   = lt ? ci  : bi[p];
            best[p] = lt ? key : best[p];
        }
    }

#pragma unroll
    for (int p = 0; p < PPT; ++p) {
        const float bd  = fmaxf(1.0f, sqrtf(best[p]));  // = max(1, sqrt(d2))
        const float wgt = hval[p] / bd;
        unsafeAtomicAdd(&acc[2 * bi[p] + 0], fr      * wgt);
        unsafeAtomicAdd(&acc[2 * bi[p] + 1], colf[p] * wgt);
    }
    __syncthreads();

    // one global atomic per accumulator slot per block (256 slots == TPB)
    unsafeAtomicAdd(&next[tid], acc[tid]);
}

extern "C" void kernel_launch(void* const* d_in, const int* in_sizes, int n_in,
                              void* d_out, int out_size, void* d_ws, size_t ws_size,
                              hipStream_t stream) {
    const float* clusters = (const float*)d_in[0];  // [C,2] = 256 floats
    const float* heatmap  = (const float*)d_in[1];  // [H,W] = 1M floats
    float* out  = (float*)d_out;                    // [C,2] = 256 floats
    float* bufA = (float*)d_ws;
    float* bufB = bufA + 2 * C;

    // seed ping-pong with the input clusters
    hipMemcpyAsync(bufA, clusters, 2 * C * sizeof(float),
                   hipMemcpyDeviceToDevice, stream);

    const float* src = bufA;
    for (int it = 0; it < N_ITER; ++it) {
        float* dst = (it == N_ITER - 1) ? out : ((it & 1) ? bufA : bufB);
        hipMemsetAsync(dst, 0, 2 * C * sizeof(float), stream);
        kmeans_step<<<H, TPB, 0, stream>>>(src, heatmap, dst);
        src = dst;
    }
}